// Round 1
// 127.734 us; speedup vs baseline: 1.1626x; 1.1626x over previous
//
#include <hip/hip_runtime.h>
#include <cstdint>
#include <cstddef>
#include <cmath>

static constexpr int C = 256;
static constexpr int N = 1024;
static constexpr int M = 4;                         // T*B
static constexpr size_t PLANE = (size_t)M * C * N;  // 1M elements per branch

typedef unsigned short u16;
typedef u16      u16x8 __attribute__((ext_vector_type(8)));
typedef u16      u16x4 __attribute__((ext_vector_type(4)));
typedef _Float16 f16x8 __attribute__((ext_vector_type(8)));
typedef float    f32x4 __attribute__((ext_vector_type(4)));

static constexpr int FSTR = 40;                         // LDS k-stride (u16): 80B rows, 16B aligned, conflict-free b128
static constexpr size_t LVX = (size_t)8 * 1024 * 256;   // xyT elements per split level (8 planes)
static constexpr size_t LVW = (size_t)4 * 256 * 256;    // wsp elements per split level (4 matrices)

// ---------------------------------------------------------------------------
// 3-level f16 split: v ~= h0 + h1*2^-12 + h2*2^-24  (levels scaled to normal
// f16 range; level-0 flushed below 2^-14 so no f16 denormal ever feeds MFMA
// at a magnitude that matters). Residual <= ~2^-33 * |v|.
// ---------------------------------------------------------------------------
__device__ __forceinline__ void split3(float v, u16 &h0, u16 &h1, u16 &h2)
{
    union { _Float16 f; u16 u; } cv;
    float a0 = (fabsf(v) >= 6.103515625e-05f) ? v : 0.0f;   // 2^-14 guard
    cv.f = (_Float16)a0;                 h0 = cv.u;
    float f0 = (float)cv.f;
    float r1 = v - f0;
    cv.f = (_Float16)(r1 * 4096.0f);     h1 = cv.u;
    float f1 = (float)cv.f * 2.44140625e-4f;                // *2^-12
    float r2 = r1 - f1;
    cv.f = (_Float16)(r2 * 16777216.0f); h2 = cv.u;
}

// ---------------------------------------------------------------------------
// Runtime-probe the C/D register->(row,col) mapping of mfma_f32_16x16x32_f16.
// A = row-index at k=0, B = ones at k=0  -> D[m][n] = m  (row map)
// A = ones at k=0, B = col-index at k=0  -> D[m][n] = n  (col map)
// Self-consistent regardless of operand-role conventions.
// ---------------------------------------------------------------------------
__device__ __forceinline__ void probe16(int lane, int rowv[4], int colv[4])
{
    f16x8 ar, one, bn;
    #pragma unroll
    for (int i = 0; i < 8; ++i){ ar[i]=(_Float16)0.f; one[i]=(_Float16)0.f; bn[i]=(_Float16)0.f; }
    if (lane < 16){
        ar[0]  = (_Float16)(float)lane;
        one[0] = (_Float16)1.0f;
        bn[0]  = (_Float16)(float)lane;
    }
    f32x4 z = (f32x4){0.f,0.f,0.f,0.f};
    f32x4 dr = __builtin_amdgcn_mfma_f32_16x16x32_f16(ar,  one, z, 0, 0, 0);
    f32x4 dc = __builtin_amdgcn_mfma_f32_16x16x32_f16(one, bn,  z, 0, 0, 0);
    #pragma unroll
    for (int r = 0; r < 4; ++r){ rowv[r] = (int)dr[r]; colv[r] = (int)dc[r]; }
}

// ---------------------------------------------------------------------------
// Prekernel: z=0..7  -> transpose+split x/y planes into xyT[lv][plane][n][c]
//            z=8..11 -> split Wq/Wk/Wv/Wp into wsp[lv][mat][o][c]
// ---------------------------------------------------------------------------
__global__ __launch_bounds__(256) void split_pre(
    const float* __restrict__ x, const float* __restrict__ y,
    const float* __restrict__ Wq, const float* __restrict__ Wk,
    const float* __restrict__ Wv, const float* __restrict__ Wp,
    u16* __restrict__ xyT, u16* __restrict__ wsp)
{
    const int z = blockIdx.z, tid = threadIdx.x;
    if (z < 8){
        const float* __restrict__ src = (z < 4) ? (x + (size_t)z * C * N)
                                                : (y + (size_t)(z - 4) * C * N);
        const int n0 = blockIdx.x * 64, c0 = blockIdx.y * 64;
        __shared__ float Ls[64][65];
        const int cr = tid >> 2, q = tid & 3;
        #pragma unroll
        for (int j = 0; j < 4; ++j){
            float4 vv = *(const float4*)(src + (size_t)(c0 + cr) * N + n0 + q * 16 + j * 4);
            *(float4*)&Ls[cr][q * 16 + j * 4] = vv;
        }
        __syncthreads();
        const int nr = tid >> 2, cq = tid & 3;
        u16 h0[16], h1[16], h2[16];
        #pragma unroll
        for (int e = 0; e < 16; ++e)
            split3(Ls[cq * 16 + e][nr], h0[e], h1[e], h2[e]);
        const size_t base = (size_t)z * (1024 * 256) + (size_t)(n0 + nr) * C + c0 + cq * 16;
        u16x8 t0, t1;
        #pragma unroll
        for (int i = 0; i < 8; ++i){ t0[i] = h0[i]; t1[i] = h0[8 + i]; }
        *(u16x8*)(xyT + base) = t0;            *(u16x8*)(xyT + base + 8) = t1;
        #pragma unroll
        for (int i = 0; i < 8; ++i){ t0[i] = h1[i]; t1[i] = h1[8 + i]; }
        *(u16x8*)(xyT + LVX + base) = t0;      *(u16x8*)(xyT + LVX + base + 8) = t1;
        #pragma unroll
        for (int i = 0; i < 8; ++i){ t0[i] = h2[i]; t1[i] = h2[8 + i]; }
        *(u16x8*)(xyT + 2 * LVX + base) = t0;  *(u16x8*)(xyT + 2 * LVX + base + 8) = t1;
    } else {
        const float* __restrict__ Wm = (z == 8) ? Wq : (z == 9) ? Wk : (z == 10) ? Wv : Wp;
        const int idx = ((blockIdx.y * 16 + blockIdx.x) * 256 + tid) * 4;
        float4 vv = *(const float4*)(Wm + idx);
        const size_t base = (size_t)(z - 8) * 65536 + idx;
        u16x4 o0_, o1_, o2_;
        u16 a, b, c2;
        split3(vv.x, a, b, c2); o0_[0]=a; o1_[0]=b; o2_[0]=c2;
        split3(vv.y, a, b, c2); o0_[1]=a; o1_[1]=b; o2_[1]=c2;
        split3(vv.z, a, b, c2); o0_[2]=a; o1_[2]=b; o2_[2]=c2;
        split3(vv.w, a, b, c2); o0_[3]=a; o1_[3]=b; o2_[3]=c2;
        *(u16x4*)(wsp + base) = o0_;
        *(u16x4*)(wsp + LVW + base) = o1_;
        *(u16x4*)(wsp + 2 * LVW + base) = o2_;
    }
}

// ---------------------------------------------------------------------------
// qkv GEMM, f16 split-MFMA: H[m][o][n] = sum_c W[o][c]*X[m][c][n], fp32 out.
// Block 64(o) x 64(n), 4 waves of 32x32 (2x2 16x16x32 accs), K-chunk 32,
// double-buffered LDS, one barrier/chunk. 6 cross terms -> hi/mid/lo accs;
// hi drained to fp64 every 2 chunks. grid = (16, 4, 12 = br*4+m).
// ---------------------------------------------------------------------------
__global__ __launch_bounds__(256, 2) void gemm_qkv_f16(
    const u16* __restrict__ xyT, const u16* __restrict__ wsp,
    float* __restrict__ hbase)
{
    const int bz = blockIdx.z, br = bz >> 2, m = bz & 3;
    const int plane = (br == 0) ? m : 4 + m;
    const u16* __restrict__ Xl = xyT + (size_t)plane * 1024 * 256;
    const u16* __restrict__ Wl = wsp + (size_t)br * 65536;
    float* __restrict__ H = hbase + (size_t)br * PLANE + (size_t)m * C * N;

    const int n0 = blockIdx.x * 64, o0 = blockIdx.y * 64;
    const int tid = threadIdx.x, lane = tid & 63, w = tid >> 6;
    const int ow = (w & 1) * 32, nw = (w >> 1) * 32, lm = lane & 15, lk = lane >> 4;

    int rowv[4], colv[4];
    probe16(lane, rowv, colv);

    __shared__ __align__(16) u16 As[2][3][64 * FSTR];
    __shared__ __align__(16) u16 Bs[2][3][64 * FSTR];

    f32x4 ah[2][2], am2[2][2], al[2][2];
    double hs[2][2][4];
    #pragma unroll
    for (int i = 0; i < 2; ++i)
        #pragma unroll
        for (int j = 0; j < 2; ++j){
            ah[i][j] = (f32x4){0.f,0.f,0.f,0.f};
            am2[i][j] = (f32x4){0.f,0.f,0.f,0.f};
            al[i][j] = (f32x4){0.f,0.f,0.f,0.f};
            #pragma unroll
            for (int r = 0; r < 4; ++r) hs[i][j][r] = 0.0;
        }

    const int rA = tid >> 2, c8 = (tid & 3) * 8;
    u16x8 aR[3], bR[3];
    #pragma unroll
    for (int lv = 0; lv < 3; ++lv){
        aR[lv] = *(const u16x8*)(Wl + (size_t)lv * LVW + (size_t)(o0 + rA) * C + c8);
        bR[lv] = *(const u16x8*)(Xl + (size_t)lv * LVX + (size_t)(n0 + rA) * C + c8);
    }

    int buf = 0;
    for (int ch = 0; ch < 8; ++ch){
        #pragma unroll
        for (int lv = 0; lv < 3; ++lv){
            *(u16x8*)&As[buf][lv][rA * FSTR + c8] = aR[lv];
            *(u16x8*)&Bs[buf][lv][rA * FSTR + c8] = bR[lv];
        }
        __syncthreads();
        if (ch < 7){
            const int cc = (ch + 1) * 32;
            #pragma unroll
            for (int lv = 0; lv < 3; ++lv){
                aR[lv] = *(const u16x8*)(Wl + (size_t)lv * LVW + (size_t)(o0 + rA) * C + cc + c8);
                bR[lv] = *(const u16x8*)(Xl + (size_t)lv * LVX + (size_t)(n0 + rA) * C + cc + c8);
            }
        }
        f16x8 af[2][3], bf[2][3];
        #pragma unroll
        for (int ot = 0; ot < 2; ++ot)
            #pragma unroll
            for (int lv = 0; lv < 3; ++lv)
                af[ot][lv] = *(const f16x8*)&As[buf][lv][(ow + ot * 16 + lm) * FSTR + lk * 8];
        #pragma unroll
        for (int nt = 0; nt < 2; ++nt)
            #pragma unroll
            for (int lv = 0; lv < 3; ++lv)
                bf[nt][lv] = *(const f16x8*)&Bs[buf][lv][(nw + nt * 16 + lm) * FSTR + lk * 8];
        #pragma unroll
        for (int ot = 0; ot < 2; ++ot)
            #pragma unroll
            for (int nt = 0; nt < 2; ++nt){
                ah[ot][nt]  = __builtin_amdgcn_mfma_f32_16x16x32_f16(af[ot][0], bf[nt][0], ah[ot][nt], 0, 0, 0);
                am2[ot][nt] = __builtin_amdgcn_mfma_f32_16x16x32_f16(af[ot][0], bf[nt][1], am2[ot][nt], 0, 0, 0);
                am2[ot][nt] = __builtin_amdgcn_mfma_f32_16x16x32_f16(af[ot][1], bf[nt][0], am2[ot][nt], 0, 0, 0);
                al[ot][nt]  = __builtin_amdgcn_mfma_f32_16x16x32_f16(af[ot][1], bf[nt][1], al[ot][nt], 0, 0, 0);
                al[ot][nt]  = __builtin_amdgcn_mfma_f32_16x16x32_f16(af[ot][0], bf[nt][2], al[ot][nt], 0, 0, 0);
                al[ot][nt]  = __builtin_amdgcn_mfma_f32_16x16x32_f16(af[ot][2], bf[nt][0], al[ot][nt], 0, 0, 0);
            }
        if (ch & 1){
            #pragma unroll
            for (int ot = 0; ot < 2; ++ot)
                #pragma unroll
                for (int nt = 0; nt < 2; ++nt){
                    #pragma unroll
                    for (int r = 0; r < 4; ++r) hs[ot][nt][r] += (double)ah[ot][nt][r];
                    ah[ot][nt] = (f32x4){0.f,0.f,0.f,0.f};
                }
        }
        buf ^= 1;
    }

    const double S12 = 1.0 / 4096.0, S24 = 1.0 / 16777216.0;
    #pragma unroll
    for (int ot = 0; ot < 2; ++ot)
        #pragma unroll
        for (int nt = 0; nt < 2; ++nt)
            #pragma unroll
            for (int r = 0; r < 4; ++r){
                double hv = hs[ot][nt][r] + (double)am2[ot][nt][r] * S12 + (double)al[ot][nt][r] * S24;
                H[(size_t)(o0 + ow + ot * 16 + rowv[r]) * N + (n0 + nw + nt * 16 + colv[r])] = (float)hv;
            }
}

// ---------------------------------------------------------------------------
// Fused BN stats + spike for q/k/v (fp32 h input, byte spike output).
// ---------------------------------------------------------------------------
__global__ __launch_bounds__(256) void bnspike_qkv(
    const float* __restrict__ hbase,
    const float* __restrict__ gq, const float* __restrict__ bq,
    const float* __restrict__ gk, const float* __restrict__ bk,
    const float* __restrict__ gv, const float* __restrict__ bv,
    unsigned char* __restrict__ sbase)
{
    const int o = blockIdx.x, br = blockIdx.y;
    const float* __restrict__ h = hbase + (size_t)br * PLANE + (size_t)o * N;
    const int tid = threadIdx.x;

    float4 v[4];
    double s = 0.0, ss = 0.0;
    #pragma unroll
    for (int j = 0; j < 4; ++j){
        v[j] = *(const float4*)(h + (size_t)j * C * N + tid * 4);
        double a = v[j].x, b = v[j].y, c = v[j].z, d = v[j].w;
        s  += (a + b) + (c + d);
        ss += (a * a + b * b) + (c * c + d * d);
    }
    #pragma unroll
    for (int off = 32; off > 0; off >>= 1){
        s  += __shfl_down(s, off, 64);
        ss += __shfl_down(ss, off, 64);
    }
    __shared__ double rs[4], rss[4], sstat[2];
    const int lane = tid & 63, wv_ = tid >> 6;
    if (lane == 0){ rs[wv_] = s; rss[wv_] = ss; }
    __syncthreads();
    if (tid == 0){
        double S  = rs[0] + rs[1] + rs[2] + rs[3];
        double SS = rss[0] + rss[1] + rss[2] + rss[3];
        double mean = S / 4096.0;
        double var  = SS / 4096.0 - mean * mean;
        sstat[0] = mean;
        sstat[1] = 1.0 / sqrt(var + 1e-5);
    }
    __syncthreads();
    const double mean = sstat[0], inv = sstat[1];
    const float* g = (br == 0) ? gq : (br == 1) ? gk : gv;
    const float* b = (br == 0) ? bq : (br == 1) ? bk : bv;
    const double gc = (double)g[o], bc = (double)b[o];
    unsigned char* out = sbase + (size_t)br * PLANE + (size_t)o * N;
    #pragma unroll
    for (int j = 0; j < 4; ++j){
        unsigned int pk = 0;
        pk |= ((gc * ((double)v[j].x - mean) * inv + bc >= 1.0) ? 1u : 0u);
        pk |= ((gc * ((double)v[j].y - mean) * inv + bc >= 1.0) ? 1u : 0u) << 8;
        pk |= ((gc * ((double)v[j].z - mean) * inv + bc >= 1.0) ? 1u : 0u) << 16;
        pk |= ((gc * ((double)v[j].w - mean) * inv + bc >= 1.0) ? 1u : 0u) << 24;
        *(unsigned int*)(out + (size_t)j * C * N + tid * 4) = pk;
    }
}

// ---------------------------------------------------------------------------
// Fused attention: kTv via popc over packed 0/1 bytes, S = q . kTv, spike S>=2.
// Output written TRANSPOSED: s2T[t][n][c] (16 contiguous bytes per thread).
// grid = (4 n-chunks, 16 heads, 4 t).
// ---------------------------------------------------------------------------
__global__ __launch_bounds__(256) void attn_kernel(
    const unsigned char* __restrict__ qb, const unsigned char* __restrict__ kb,
    const unsigned char* __restrict__ vb, unsigned char* __restrict__ s2T)
{
    const int nc = blockIdx.x;
    const int hh = blockIdx.y;
    const int t  = blockIdx.z;
    const int tid = threadIdx.x;

    __shared__ unsigned int kw[16][257];
    __shared__ unsigned int vw[16][257];
    __shared__ int kt[256];

    #pragma unroll
    for (int j = 0; j < 4; ++j){
        int idx = j * 256 + tid;
        int r = idx >> 6, q4 = idx & 63;
        size_t goff = ((size_t)(t * C + hh * 16 + r)) * N + (size_t)q4 * 16;
        uint4 kk = *(const uint4*)(kb + goff);
        uint4 vv = *(const uint4*)(vb + goff);
        kw[r][q4 * 4 + 0] = kk.x; kw[r][q4 * 4 + 1] = kk.y;
        kw[r][q4 * 4 + 2] = kk.z; kw[r][q4 * 4 + 3] = kk.w;
        vw[r][q4 * 4 + 0] = vv.x; vw[r][q4 * 4 + 1] = vv.y;
        vw[r][q4 * 4 + 2] = vv.z; vw[r][q4 * 4 + 3] = vv.w;
    }
    __syncthreads();

    const int d = tid >> 4, dp = tid & 15;
    int sum = 0;
    #pragma unroll 8
    for (int wd = 0; wd < 256; ++wd)
        sum += __popc(kw[d][wd] & vw[dp][wd]);
    kt[tid] = sum;
    __syncthreads();

    const int n = nc * 256 + tid;
    int sums[16];
    #pragma unroll
    for (int i = 0; i < 16; ++i) sums[i] = 0;
    #pragma unroll
    for (int d2 = 0; d2 < 16; ++d2){
        int qv = (int)qb[((size_t)(t * C + hh * 16 + d2)) * N + n];
        #pragma unroll
        for (int dp2 = 0; dp2 < 16; ++dp2)
            sums[dp2] += qv * kt[d2 * 16 + dp2];
    }
    uint4 ov;
    unsigned int* ovp = (unsigned int*)&ov;
    #pragma unroll
    for (int g = 0; g < 4; ++g){
        unsigned int wv2 = 0;
        #pragma unroll
        for (int e = 0; e < 4; ++e)
            wv2 |= ((sums[g * 4 + e] >= 2) ? 1u : 0u) << (8 * e);
        ovp[g] = wv2;
    }
    *(uint4*)(s2T + ((size_t)t * N + n) * C + hh * 16) = ov;
}

// ---------------------------------------------------------------------------
// Proj GEMM, f16 split-MFMA: h[o][n] = sum_c Wp[o][c]*s2[c][n], fp32 out.
// B = binary (exact in f16, one level); A = Wp 3-level split -> essentially
// exact. Block 32(o) x 64(n), 4 waves of 16x32, K-chunk 32, dbuf.
// grid = (16, 8, 4).
// ---------------------------------------------------------------------------
__global__ __launch_bounds__(256, 2) void gemm_p_f16(
    const u16* __restrict__ wsp, const unsigned char* __restrict__ s2T,
    float* __restrict__ hp)
{
    const int m = blockIdx.z;
    const int n0 = blockIdx.x * 64, o0 = blockIdx.y * 32;
    const int tid = threadIdx.x, lane = tid & 63, w = tid >> 6;
    const int ow = (w & 1) * 16, nw = (w >> 1) * 32, lm = lane & 15, lk = lane >> 4;
    const u16* __restrict__ Wl = wsp + (size_t)3 * 65536;
    const unsigned char* __restrict__ Xb = s2T + (size_t)m * N * C;
    float* __restrict__ H = hp + (size_t)m * C * N;

    int rowv[4], colv[4];
    probe16(lane, rowv, colv);

    __shared__ __align__(16) u16 As[2][3][32 * FSTR];
    __shared__ __align__(16) u16 Bs[2][64 * FSTR];

    f32x4 a0[2], a1[2], a2[2];
    double hs[2][4];
    #pragma unroll
    for (int i = 0; i < 2; ++i){
        a0[i] = (f32x4){0.f,0.f,0.f,0.f};
        a1[i] = (f32x4){0.f,0.f,0.f,0.f};
        a2[i] = (f32x4){0.f,0.f,0.f,0.f};
        #pragma unroll
        for (int r = 0; r < 4; ++r) hs[i][r] = 0.0;
    }

    const int rA = tid >> 3, c4 = (tid & 7) * 4;
    const int rB = tid >> 2, c8 = (tid & 3) * 8;
    u16x4 aR[3];
    uint2 bw;
    #pragma unroll
    for (int lv = 0; lv < 3; ++lv)
        aR[lv] = *(const u16x4*)(Wl + (size_t)lv * LVW + (size_t)(o0 + rA) * C + c4);
    bw = *(const uint2*)(Xb + (size_t)(n0 + rB) * C + c8);

    int buf = 0;
    for (int ch = 0; ch < 8; ++ch){
        #pragma unroll
        for (int lv = 0; lv < 3; ++lv)
            *(u16x4*)&As[buf][lv][rA * FSTR + c4] = aR[lv];
        u16x8 bv;
        #pragma unroll
        for (int e = 0; e < 4; ++e){
            bv[e]     = (u16)(((bw.x >> (8 * e)) & 1u) * 0x3C00u);
            bv[4 + e] = (u16)(((bw.y >> (8 * e)) & 1u) * 0x3C00u);
        }
        *(u16x8*)&Bs[buf][rB * FSTR + c8] = bv;
        __syncthreads();
        if (ch < 7){
            const int cc = (ch + 1) * 32;
            #pragma unroll
            for (int lv = 0; lv < 3; ++lv)
                aR[lv] = *(const u16x4*)(Wl + (size_t)lv * LVW + (size_t)(o0 + rA) * C + cc + c4);
            bw = *(const uint2*)(Xb + (size_t)(n0 + rB) * C + cc + c8);
        }
        f16x8 af[3], bf[2];
        #pragma unroll
        for (int lv = 0; lv < 3; ++lv)
            af[lv] = *(const f16x8*)&As[buf][lv][(ow + lm) * FSTR + lk * 8];
        #pragma unroll
        for (int nt = 0; nt < 2; ++nt)
            bf[nt] = *(const f16x8*)&Bs[buf][(nw + nt * 16 + lm) * FSTR + lk * 8];
        #pragma unroll
        for (int nt = 0; nt < 2; ++nt){
            a0[nt] = __builtin_amdgcn_mfma_f32_16x16x32_f16(af[0], bf[nt], a0[nt], 0, 0, 0);
            a1[nt] = __builtin_amdgcn_mfma_f32_16x16x32_f16(af[1], bf[nt], a1[nt], 0, 0, 0);
            a2[nt] = __builtin_amdgcn_mfma_f32_16x16x32_f16(af[2], bf[nt], a2[nt], 0, 0, 0);
        }
        if (ch & 1){
            #pragma unroll
            for (int nt = 0; nt < 2; ++nt){
                #pragma unroll
                for (int r = 0; r < 4; ++r) hs[nt][r] += (double)a0[nt][r];
                a0[nt] = (f32x4){0.f,0.f,0.f,0.f};
            }
        }
        buf ^= 1;
    }

    const double S12 = 1.0 / 4096.0, S24 = 1.0 / 16777216.0;
    #pragma unroll
    for (int nt = 0; nt < 2; ++nt)
        #pragma unroll
        for (int r = 0; r < 4; ++r){
            double hv = hs[nt][r] + (double)a1[nt][r] * S12 + (double)a2[nt][r] * S24;
            H[(size_t)(o0 + ow + rowv[r]) * N + (n0 + nw + nt * 16 + colv[r])] = (float)hv;
        }
}

// ---------------------------------------------------------------------------
// Fused BN stats + spike for proj -> fp32 0/1 output (fp32 h input).
// ---------------------------------------------------------------------------
__global__ __launch_bounds__(256) void bnspike_p(
    const float* __restrict__ hp,
    const float* __restrict__ gp, const float* __restrict__ bp,
    float* __restrict__ outp)
{
    const int o = blockIdx.x;
    const float* __restrict__ h = hp + (size_t)o * N;
    const int tid = threadIdx.x;

    float4 v[4];
    double s = 0.0, ss = 0.0;
    #pragma unroll
    for (int j = 0; j < 4; ++j){
        v[j] = *(const float4*)(h + (size_t)j * C * N + tid * 4);
        double a = v[j].x, b = v[j].y, c = v[j].z, d = v[j].w;
        s  += (a + b) + (c + d);
        ss += (a * a + b * b) + (c * c + d * d);
    }
    #pragma unroll
    for (int off = 32; off > 0; off >>= 1){
        s  += __shfl_down(s, off, 64);
        ss += __shfl_down(ss, off, 64);
    }
    __shared__ double rs[4], rss[4], sstat[2];
    const int lane = tid & 63, wv_ = tid >> 6;
    if (lane == 0){ rs[wv_] = s; rss[wv_] = ss; }
    __syncthreads();
    if (tid == 0){
        double S  = rs[0] + rs[1] + rs[2] + rs[3];
        double SS = rss[0] + rss[1] + rss[2] + rss[3];
        double mean = S / 4096.0;
        double var  = SS / 4096.0 - mean * mean;
        sstat[0] = mean;
        sstat[1] = 1.0 / sqrt(var + 1e-5);
    }
    __syncthreads();
    const double mean = sstat[0], inv = sstat[1];
    const double gc = (double)gp[o], bc = (double)bp[o];
    float* out = outp + (size_t)o * N;
    #pragma unroll
    for (int j = 0; j < 4; ++j){
        float4 r;
        r.x = (gc * ((double)v[j].x - mean) * inv + bc >= 1.0) ? 1.0f : 0.0f;
        r.y = (gc * ((double)v[j].y - mean) * inv + bc >= 1.0) ? 1.0f : 0.0f;
        r.z = (gc * ((double)v[j].z - mean) * inv + bc >= 1.0) ? 1.0f : 0.0f;
        r.w = (gc * ((double)v[j].w - mean) * inv + bc >= 1.0) ? 1.0f : 0.0f;
        *(float4*)(out + (size_t)j * C * N + tid * 4) = r;
    }
}

// ---------------------------------------------------------------------------
extern "C" void kernel_launch(void* const* d_in, const int* in_sizes, int n_in,
                              void* d_out, int out_size, void* d_ws, size_t ws_size,
                              hipStream_t stream)
{
    const float* x  = (const float*)d_in[0];
    const float* y  = (const float*)d_in[1];
    const float* Wq = (const float*)d_in[2];
    const float* gq = (const float*)d_in[3];
    const float* bq = (const float*)d_in[4];
    const float* Wk = (const float*)d_in[5];
    const float* gk = (const float*)d_in[6];
    const float* bk = (const float*)d_in[7];
    const float* Wv = (const float*)d_in[8];
    const float* gv = (const float*)d_in[9];
    const float* bv = (const float*)d_in[10];
    const float* Wp = (const float*)d_in[11];
    const float* gp = (const float*)d_in[12];
    const float* bp = (const float*)d_in[13];
    float* out = (float*)d_out;

    // Workspace layout (26 MB):
    //   [0, 12MB)   xyT f16 split planes [3][8][1024][256]  (dead after gemm_qkv)
    //               ... later overlaid by qb/kb/vb/s2T bytes (4 MB)
    //   [12, 13.5)  wsp f16 split weights [3][4][256][256]
    //   [14, 26)    hq fp32 [3][PLANE]; hp fp32 [PLANE] aliases same base
    char* ws = (char*)d_ws;
    u16* xyT = (u16*)ws;
    u16* wsp = (u16*)(ws + (size_t)12 * 1024 * 1024);
    float* hq = (float*)(ws + (size_t)14 * 1024 * 1024);
    float* hp = hq;
    unsigned char* qb  = (unsigned char*)ws;
    unsigned char* kb2 = qb + PLANE;
    unsigned char* vb2 = qb + 2 * PLANE;
    unsigned char* s2b = qb + 3 * PLANE;

    split_pre<<<dim3(16, 4, 12), 256, 0, stream>>>(x, y, Wq, Wk, Wv, Wp, xyT, wsp);
    gemm_qkv_f16<<<dim3(16, 4, 12), 256, 0, stream>>>(xyT, wsp, hq);
    bnspike_qkv<<<dim3(256, 3), 256, 0, stream>>>(hq, gq, bq, gk, bk, gv, bv, qb);
    attn_kernel<<<dim3(4, 16, 4), 256, 0, stream>>>(qb, kb2, vb2, s2b);
    gemm_p_f16<<<dim3(16, 8, 4), 256, 0, stream>>>(wsp, s2b, hp);
    bnspike_p<<<dim3(256), 256, 0, stream>>>(hp, gp, bp, out);
}